// Round 6
// baseline (1435.750 us; speedup 1.0000x reference)
//
#include <hip/hip_runtime.h>
#include <hip/hip_bf16.h>

// MoE top-2-of-8 FFN + shared expert + router losses, MI355X gfx950.
// R5: router/scatter atomic de-serialization (274us -> noise).
// R8: m97-canonical 128^2 single-buffer GEMM at 4 blocks/CU (inter-block TLP
//     hides stage drain; ~1300 TF steady in the full-occupancy phase).
// R9 post-mortem: atomicAdd epilogue fusion = 1 GB HBM RMW traffic (16.7M
//     device-scope atomics ping-pong cachelines across non-coherent XCD L2s);
//     ev 210 -> 645us. REVERTED. The 5-blocks/CU launch_bounds was validated
//     (Occupancy 27 -> 35 even while atomic-stalled) and is KEPT.
// R10: R8 epilogue (bf16 eout + combine gather) + ev at 5 blocks/CU (1280
//     slots >= 1088 blocks -> single round, no 2nd-round idle) + vectorized
//     transpose writes (ushort8, verified in R9).

#define N_TOK 8192
#define DM    1024
#define HD    4096
#define NE    8
#define NKTOT 16384            // N_TOK * 2
#define PERM_CAP 17408         // NKTOT + NE*128 (segment padding)
#define MAX_TILES 136          // sum ceil(T_e/128) <= NKTOT/128 + NE
#define BAND 17                // MAX_TILES / 8 xcds
#define RTOK_BLK 16            // router tokens per block

typedef __attribute__((ext_vector_type(8))) short bhalf8;
typedef __attribute__((ext_vector_type(8))) unsigned short ushort8v;
typedef __attribute__((ext_vector_type(4))) float floatx4;

__device__ __forceinline__ unsigned short f2bf(float f) {
  union { float f; unsigned int u; } v; v.f = f;
  unsigned int u = v.u;
  return (unsigned short)((u + 0x7fffu + ((u >> 16) & 1u)) >> 16);  // RNE
}

__device__ __forceinline__ float bf2f(unsigned short h) {
  union { unsigned int u; float f; } v; v.u = ((unsigned int)h) << 16;
  return v.f;
}

__device__ __forceinline__ float gelu_tanh(float h) {
  // jax.nn.gelu default (approximate=True)
  float u = 0.7978845608028654f * (h + 0.044715f * h * h * h);
  float t = 1.0f - 2.0f / (1.0f + __expf(2.0f * u));   // tanh(u)
  return 0.5f * h * (1.0f + t);
}

// global -> LDS direct DMA, 16B/lane. LDS dest is wave-uniform base + lane*16.
__device__ __forceinline__ void gload16(const unsigned short* g, void* l) {
  __builtin_amdgcn_global_load_lds(
      (const __attribute__((address_space(1))) void*)g,
      (__attribute__((address_space(3))) void*)l, 16, 0, 0);
}

// ---------------- init (ws is poisoned 0xAA each call) ----------------
__global__ void init_kernel(int* perm, float* permw, float* usage, float* zsum,
                            int* counts, int* fill) {
  int i = blockIdx.x * 256 + threadIdx.x;
  if (i < PERM_CAP) { perm[i] = 0; permw[i] = 0.0f; }
  if (i < NE) { usage[i] = 0.0f; counts[i] = 0; fill[i] = 0; }
  if (i == 0) zsum[0] = 0.0f;
}

// ---------------- x fp32 -> bf16 ----------------
__global__ void cvt_x_kernel(const float* __restrict__ x, unsigned short* __restrict__ xb) {
  size_t i = (size_t)(blockIdx.x * 256 + threadIdx.x) * 4;
  float4 v = *(const float4*)(x + i);
  ushort4 o;
  o.x = f2bf(v.x); o.y = f2bf(v.y); o.z = f2bf(v.z); o.w = f2bf(v.w);
  *(ushort4*)(xb + i) = o;
}

// ---------------- router: logits, top-2 softmax, aux-loss partials ----------------
__global__ void router_kernel(const float* __restrict__ x, const float* __restrict__ gw,
                              int* __restrict__ idxb, float* __restrict__ wbuf,
                              float* __restrict__ usage, float* __restrict__ zsum,
                              int* __restrict__ counts) {
  __shared__ float s_use[NE];
  __shared__ int   s_cnt[NE];
  __shared__ float s_z;
  int t = threadIdx.x;
  if (t < NE) { s_use[t] = 0.0f; s_cnt[t] = 0; }
  if (t == 0) s_z = 0.0f;
  __syncthreads();

  int wave = t >> 6;
  int lane = t & 63;

  float luse[NE]; int lcnt[NE];
#pragma unroll
  for (int e = 0; e < NE; e++) { luse[e] = 0.0f; lcnt[e] = 0; }
  float lz = 0.0f;

#pragma unroll
  for (int i = 0; i < 4; i++) {
    int n = blockIdx.x * RTOK_BLK + wave * 4 + i;
    const float* xr = x + (size_t)n * DM;
    float acc[NE];
#pragma unroll
    for (int e = 0; e < NE; e++) acc[e] = 0.0f;
    for (int d = lane; d < DM; d += 64) {
      float xv = xr[d];
      const float* g = gw + (size_t)d * NE;
#pragma unroll
      for (int e = 0; e < NE; e++) acc[e] += xv * g[e];
    }
#pragma unroll
    for (int e = 0; e < NE; e++) {
#pragma unroll
      for (int off = 32; off > 0; off >>= 1) acc[e] += __shfl_xor(acc[e], off);
    }
    if (lane == 0) {
      float m1 = acc[0]; int i1 = 0;
#pragma unroll
      for (int e = 1; e < NE; e++) if (acc[e] > m1) { m1 = acc[e]; i1 = e; }
      float m2 = -3.0e38f; int i2 = 0;
#pragma unroll
      for (int e = 0; e < NE; e++) if (e != i1 && acc[e] > m2) { m2 = acc[e]; i2 = e; }
      float e1 = __expf(m2 - m1);
      float w1 = 1.0f / (1.0f + e1);
      float w2 = e1 / (1.0f + e1);
      float s = 0.0f;
#pragma unroll
      for (int e = 0; e < NE; e++) s += __expf(acc[e] - m1);
      float lse = m1 + __logf(s);
      idxb[n * 2 + 0] = i1; idxb[n * 2 + 1] = i2;
      wbuf[n * 2 + 0] = w1; wbuf[n * 2 + 1] = w2;
      luse[i1] += w1; luse[i2] += w2;
      lcnt[i1]++;     lcnt[i2]++;
      lz += lse * lse;
    }
  }

  if (lane == 0) {
#pragma unroll
    for (int e = 0; e < NE; e++) {
      atomicAdd(&s_use[e], luse[e]);
      atomicAdd(&s_cnt[e], lcnt[e]);
    }
    atomicAdd(&s_z, lz);
  }
  __syncthreads();
  if (t < NE) {
    atomicAdd(&usage[t], s_use[t]);
    atomicAdd(&counts[t], s_cnt[t]);
  }
  if (t == 0) atomicAdd(zsum, s_z);
}

// ---------------- scan: padded segment offsets, tile table, router loss ----------------
__global__ void scan_kernel(const int* __restrict__ counts, int* __restrict__ poff,
                            int* __restrict__ tileE, int* __restrict__ tileR,
                            int* __restrict__ nTiles,
                            const float* __restrict__ usage, const float* __restrict__ zsum,
                            float* __restrict__ lossOut) {
  if (threadIdx.x == 0 && blockIdx.x == 0) {
    int run = 0, nt = 0;
    for (int e = 0; e < NE; e++) {
      poff[e] = run;
      int t = (counts[e] + 127) >> 7;
      for (int i = 0; i < t; i++) { tileE[nt] = e; tileR[nt] = run + i * 128; nt++; }
      run += t << 7;
    }
    *nTiles = nt;
    float mean = 0.0f;
    for (int e = 0; e < NE; e++) mean += usage[e];
    mean *= (1.0f / NE);
    float var = 0.0f;
    for (int e = 0; e < NE; e++) { float d = usage[e] - mean; var += d * d; }
    var *= (1.0f / NE);
    float bal = sqrtf(var) / mean * 0.01f;
    float z = (zsum[0] / (float)N_TOK) * 0.001f;
    lossOut[0] = bal + z;
  }
}

// ---------------- scatter tokens into per-expert segments ----------------
__global__ void scatter_kernel(const int* __restrict__ idxb, const float* __restrict__ wbuf,
                               const int* __restrict__ poff, int* __restrict__ fill,
                               int* __restrict__ perm, float* __restrict__ permw,
                               int* __restrict__ pos) {
  __shared__ int lcnt[NE];
  __shared__ int lbase[NE];
  int t = threadIdx.x;
  if (t < NE) lcnt[t] = 0;
  __syncthreads();
  int i = blockIdx.x * 256 + t;          // grid sized exactly: i < NKTOT
  int e = idxb[i];
  int r = atomicAdd(&lcnt[e], 1);        // LDS rank within block
  __syncthreads();
  if (t < NE) lbase[t] = atomicAdd(&fill[t], lcnt[t]);
  __syncthreads();
  int p = poff[e] + lbase[e] + r;
  perm[p] = i >> 1;
  permw[p] = wbuf[i];
  pos[i] = p;
}

// ---------------- transpose+convert: src fp32 [R][C] -> dst bf16 [C][R], batched ----------------
// dst writes vectorized: each lane stores ushort8 (16B). LDS read stride 65
// words -> 8 consecutive rows hit 8 distinct banks (conflict-free).
__global__ void transpose_cvt_kernel(const float* __restrict__ src,
                                     unsigned short* __restrict__ dst, int R, int C) {
  __shared__ float tile[64][65];
  size_t bo = (size_t)blockIdx.z * R * C;
  src += bo; dst += bo;
  int r0 = blockIdx.x * 64, c0 = blockIdx.y * 64;
  int c = threadIdx.x & 63, r = threadIdx.x >> 6;
#pragma unroll
  for (int i = 0; i < 16; i++)
    tile[r + i * 4][c] = src[(size_t)(r0 + r + i * 4) * C + c0 + c];
  __syncthreads();
  int u = threadIdx.x & 7;        // dst 8-col group (src row group)
  int ow = threadIdx.x >> 3;      // 0..31: dst row offset base
#pragma unroll
  for (int it = 0; it < 2; it++) {
    int oc = ow + it * 32;        // src col -> dst row offset
    ushort8v o;
#pragma unroll
    for (int j = 0; j < 8; j++) o[j] = f2bf(tile[u * 8 + j][oc]);
    *(ushort8v*)&dst[(size_t)(c0 + oc) * R + r0 + u * 8] = o;
  }
}

// ---------------- combine: out[t] += eout[pos0[t]] + eout[pos1[t]] ----------------
__global__ void combine_kernel(float* __restrict__ out,
                               const unsigned short* __restrict__ eout,
                               const int* __restrict__ pos) {
  int t = blockIdx.x;
  int d = threadIdx.x * 8;
  int p0 = pos[t * 2], p1 = pos[t * 2 + 1];
  float* o = out + (size_t)t * DM + d;
  const unsigned short* e0 = eout + (size_t)p0 * DM + d;
  const unsigned short* e1 = eout + (size_t)p1 * DM + d;
  float4 a = *(const float4*)(o);
  float4 b = *(const float4*)(o + 4);
  ushort4 u0a = *(const ushort4*)(e0), u0b = *(const ushort4*)(e0 + 4);
  ushort4 u1a = *(const ushort4*)(e1), u1b = *(const ushort4*)(e1 + 4);
  a.x += bf2f(u0a.x) + bf2f(u1a.x);
  a.y += bf2f(u0a.y) + bf2f(u1a.y);
  a.z += bf2f(u0a.z) + bf2f(u1a.z);
  a.w += bf2f(u0a.w) + bf2f(u1a.w);
  b.x += bf2f(u0b.x) + bf2f(u1b.x);
  b.y += bf2f(u0b.y) + bf2f(u1b.y);
  b.z += bf2f(u0b.z) + bf2f(u1b.z);
  b.w += bf2f(u0b.w) + bf2f(u1b.w);
  *(float4*)(o) = a;
  *(float4*)(o + 4) = b;
}

// ---------------- 128x128xBK64 bf16 MFMA GEMM, m97-canonical single buffer ----------------
// 256 threads = 4 waves (2x2 of 64x64 wave tiles). LDS: A[128][64]+B[128][64]
// bf16 = 32 KB. Per K-step: stage (8 x global_load_lds dwordx4) ->
// __syncthreads (drains vmcnt) -> 2x 16x16x32 k-steps of 4x4 MFMA ->
// __syncthreads. Stage drain hidden by co-resident sibling blocks (TLP).
template<int MODE>
__device__ __forceinline__ void gemm_body(
    const unsigned short* __restrict__ A,
    const unsigned short* __restrict__ BT,
    const float* __restrict__ bias,
    float* __restrict__ outF,
    unsigned short* __restrict__ outH,
    int Kd, int Nd,
    const int* __restrict__ perm,
    const float* __restrict__ permw,
    const int* __restrict__ tileE,
    const int* __restrict__ tileR,
    const int* __restrict__ nTiles) {
  __shared__ __align__(16) unsigned short As[128 * 64];
  __shared__ __align__(16) unsigned short Bs[128 * 64];

  int id = blockIdx.x;
  int xcd = id & 7, q = id >> 3;
  int mt, ntile;
  if (MODE == 0) {              // band 8m, m-fastest: pin A-band + B-slab in L2
    mt = xcd * 8 + (q & 7);
    ntile = q >> 3;
  } else if (MODE == 1) {       // band 8m, n-fastest
    ntile = q & 7;
    mt = xcd * 8 + (q >> 3);
  } else if (MODE == 2) {       // band 17m, supertile 4m x 8n
    int n_in = q & 7, m_in = (q >> 3) & 3, ng = (q >> 5) & 3, mg = q >> 7;
    int mband = mg * 4 + m_in;
    if (mband >= BAND) return;
    mt = xcd * BAND + mband;
    ntile = ng * 8 + n_in;
  } else {                      // band 17m, n-fastest per m
    mt = xcd * BAND + (q >> 3);
    ntile = q & 7;
  }

  int n0 = ntile * 128;
  int prow0 = 0, m0 = 0;
  if (MODE >= 2) {
    if (mt >= *nTiles) return;
    int e = tileE[mt];
    prow0 = tileR[mt];
    BT += (size_t)e * Kd * Nd;
    bias += (size_t)e * Nd;
  } else {
    m0 = mt * 128;
  }

  int t = threadIdx.x;
  int rsub = t >> 3;               // 0..31: row within 32-row staging slab
  int gc = (t & 7) ^ (rsub & 7);   // swizzled global 16B-chunk index
  const unsigned short* aptr[4];
  const unsigned short* bptr[4];
#pragma unroll
  for (int p = 0; p < 4; p++) {
    int r = rsub + p * 32;
    size_t grow;
    if (MODE == 2)      grow = (size_t)perm[prow0 + r];
    else if (MODE == 3) grow = (size_t)(prow0 + r);
    else                grow = (size_t)(m0 + r);
    aptr[p] = A + grow * Kd + gc * 8;
    bptr[p] = BT + (size_t)(n0 + r) * Kd + gc * 8;
  }
  // wave-uniform LDS staging bases (lane*16 is added by HW)
  char* ldsA = (char*)As + (t & 192) * 16;
  char* ldsB = (char*)Bs + (t & 192) * 16;

  int lane = t & 63;
  int wv = t >> 6;
  int wm = (wv >> 1) * 64, wn = (wv & 1) * 64;
  int lr = lane & 15, lq = lane >> 4;
  int rx = lr & 7;                  // read-side row XOR key

  floatx4 acc[4][4];
#pragma unroll
  for (int i = 0; i < 4; i++)
#pragma unroll
    for (int j = 0; j < 4; j++) acc[i][j] = (floatx4){0.f, 0.f, 0.f, 0.f};

  for (int k0 = 0; k0 < Kd; k0 += 64) {
#pragma unroll
    for (int p = 0; p < 4; p++) {
      gload16(aptr[p] + k0, ldsA + p * 4096);
      gload16(bptr[p] + k0, ldsB + p * 4096);
    }
    __syncthreads();               // drains vmcnt(0): tile staged
#pragma unroll
    for (int kk = 0; kk < 2; kk++) {       // two 16x16x32 k-steps
      int ca = kk * 4 + lq;                // global chunk for this frag
      bhalf8 af[4], bf[4];
#pragma unroll
      for (int i = 0; i < 4; i++) {
        af[i] = *(const bhalf8*)&As[(wm + i * 16 + lr) * 64 + ((ca ^ rx) * 8)];
        bf[i] = *(const bhalf8*)&Bs[(wn + i * 16 + lr) * 64 + ((ca ^ rx) * 8)];
      }
#pragma unroll
      for (int mtile = 0; mtile < 4; mtile++)
#pragma unroll
        for (int ntl = 0; ntl < 4; ntl++)
          acc[mtile][ntl] = __builtin_amdgcn_mfma_f32_16x16x32_bf16(af[mtile], bf[ntl], acc[mtile][ntl], 0, 0, 0);
    }
    __syncthreads();               // protect buffer before next stage
  }

  // epilogue: D[row=(lane>>4)*4+reg][col=lane&15]
#pragma unroll
  for (int mtile = 0; mtile < 4; mtile++) {
#pragma unroll
    for (int ntl = 0; ntl < 4; ntl++) {
      int ncol = n0 + wn + ntl * 16 + lr;
      float bb = bias[ncol];
#pragma unroll
      for (int r = 0; r < 4; r++) {
        int mrow = wm + mtile * 16 + lq * 4 + r;    // local row 0..127
        float v = acc[mtile][ntl][r] + bb;
        if (MODE == 0) {
          outH[(size_t)(m0 + mrow) * Nd + ncol] = f2bf(gelu_tanh(v));
        } else if (MODE == 1) {
          outF[(size_t)(m0 + mrow) * Nd + ncol] = v;
        } else if (MODE == 2) {
          outH[(size_t)(prow0 + mrow) * Nd + ncol] = f2bf(gelu_tanh(v));
        } else {
          int prow = prow0 + mrow;
          float w = permw[prow];
          outH[(size_t)prow * Nd + ncol] = f2bf(w * v);   // weighted expert out
        }
      }
    }
  }
}

// distinct names per mode so rocprof shows the per-GEMM breakdown
__global__ __launch_bounds__(256, 4) void gemm_shared_keys(
    const unsigned short* A, const unsigned short* BT, const float* bias,
    float* outF, unsigned short* outH, int Kd, int Nd,
    const int* perm, const float* permw, const int* tE, const int* tR, const int* nT) {
  gemm_body<0>(A, BT, bias, outF, outH, Kd, Nd, perm, permw, tE, tR, nT);
}
__global__ __launch_bounds__(256, 4) void gemm_shared_values(
    const unsigned short* A, const unsigned short* BT, const float* bias,
    float* outF, unsigned short* outH, int Kd, int Nd,
    const int* perm, const float* permw, const int* tE, const int* tR, const int* nT) {
  gemm_body<1>(A, BT, bias, outF, outH, Kd, Nd, perm, permw, tE, tR, nT);
}
__global__ __launch_bounds__(256, 4) void gemm_expert_keys(
    const unsigned short* A, const unsigned short* BT, const float* bias,
    float* outF, unsigned short* outH, int Kd, int Nd,
    const int* perm, const float* permw, const int* tE, const int* tR, const int* nT) {
  gemm_body<2>(A, BT, bias, outF, outH, Kd, Nd, perm, permw, tE, tR, nT);
}
// 32KB LDS -> exactly 5 blocks/CU: 1280 slots >= 1088 blocks -> single round.
__global__ __launch_bounds__(256, 5) void gemm_expert_values(
    const unsigned short* A, const unsigned short* BT, const float* bias,
    float* outF, unsigned short* outH, int Kd, int Nd,
    const int* perm, const float* permw, const int* tE, const int* tR, const int* nT) {
  gemm_body<3>(A, BT, bias, outF, outH, Kd, Nd, perm, permw, tE, tR, nT);
}

extern "C" void kernel_launch(void* const* d_in, const int* in_sizes, int n_in,
                              void* d_out, int out_size, void* d_ws, size_t ws_size,
                              hipStream_t stream) {
  const float* x        = (const float*)d_in[0];
  const float* gate_w   = (const float*)d_in[1];
  const float* keys_w   = (const float*)d_in[2];
  const float* keys_b   = (const float*)d_in[3];
  const float* values_w = (const float*)d_in[4];
  const float* values_b = (const float*)d_in[5];
  const float* sk_w     = (const float*)d_in[6];
  const float* sk_b     = (const float*)d_in[7];
  const float* sv_w     = (const float*)d_in[8];
  const float* sv_b     = (const float*)d_in[9];
  float* out = (float*)d_out;

  char* p = (char*)d_ws;
  unsigned short* xb   = (unsigned short*)p; p += (size_t)N_TOK * DM * 2;     // 16 MB
  unsigned short* wt   = (unsigned short*)p; p += (size_t)NE * DM * HD * 2;   // 64 MB (phased)
  unsigned short* hid  = (unsigned short*)p; p += (size_t)PERM_CAP * HD * 2;  // 142.6 MB
  unsigned short* eout = (unsigned short*)p; p += (size_t)PERM_CAP * DM * 2;  // 35.7 MB
  int*   idxb   = (int*)p;   p += NKTOT * 4;
  float* wbuf   = (float*)p; p += NKTOT * 4;
  int*   perm   = (int*)p;   p += PERM_CAP * 4;
  float* permw  = (float*)p; p += PERM_CAP * 4;
  int*   pos    = (int*)p;   p += NKTOT * 4;
  int*   counts = (int*)p;   p += NE * 4;
  int*   fill   = (int*)p;   p += NE * 4;
  int*   poff   = (int*)p;   p += NE * 4;
  float* usage  = (float*)p; p += NE * 4;
  float* zsum   = (float*)p; p += 16;
  int*   tileE  = (int*)p;   p += MAX_TILES * 4;
  int*   tileR  = (int*)p;   p += MAX_TILES * 4;
  int*   nTiles = (int*)p;   p += 16;

  float* lossOut = out + (size_t)N_TOK * DM;

  // 1) init + convert + router
  init_kernel<<<(PERM_CAP + 255) / 256, 256, 0, stream>>>(perm, permw, usage, zsum, counts, fill);
  cvt_x_kernel<<<(N_TOK * DM / 4 + 255) / 256, 256, 0, stream>>>(x, xb);
  router_kernel<<<N_TOK / RTOK_BLK, 256, 0, stream>>>(x, gate_w, idxb, wbuf, usage, zsum, counts);
  scan_kernel<<<1, 64, 0, stream>>>(counts, poff, tileE, tileR, nTiles, usage, zsum, lossOut);
  scatter_kernel<<<NKTOT / 256, 256, 0, stream>>>(idxb, wbuf, poff, fill, perm, permw, pos);

  // 2) shared expert: hid = gelu(x @ Wk + b); out = hid @ Wv + b
  transpose_cvt_kernel<<<dim3(DM / 64, HD / 64, 1), 256, 0, stream>>>(sk_w, wt, DM, HD);
  gemm_shared_keys<<<2048, 256, 0, stream>>>(             // 8 xcd * 8 m * 32 n (2 exact rounds)
      xb, wt, sk_b, nullptr, hid, DM, HD, perm, permw, tileE, tileR, nTiles);
  transpose_cvt_kernel<<<dim3(HD / 64, DM / 64, 1), 256, 0, stream>>>(sv_w, wt, HD, DM);
  gemm_shared_values<<<512, 256, 0, stream>>>(            // 8 xcd * 8 m * 8 n
      hid, wt, sv_b, out, nullptr, HD, DM, perm, permw, tileE, tileR, nTiles);

  // 3) routed experts (grouped, sparse top-2)
  transpose_cvt_kernel<<<dim3(DM / 64, HD / 64, NE), 256, 0, stream>>>(keys_w, wt, DM, HD);
  gemm_expert_keys<<<5120, 256, 0, stream>>>(             // 8 xcd * 20(m pad) * 32 n
      xb, wt, keys_b, nullptr, hid, DM, HD, perm, permw, tileE, tileR, nTiles);
  transpose_cvt_kernel<<<dim3(HD / 64, DM / 64, NE), 256, 0, stream>>>(values_w, wt, HD, DM);
  gemm_expert_values<<<1088, 256, 0, stream>>>(           // 8 xcd * 17 m * 8 n (1 round @5/CU)
      hid, wt, values_b, nullptr, eout, HD, DM, perm, permw, tileE, tileR, nTiles);

  // 4) out += top-2 expert contributions
  combine_kernel<<<N_TOK, 128, 0, stream>>>(out, eout, pos);
}

// Round 7
// 952.095 us; speedup vs baseline: 1.5080x; 1.5080x over previous
//
#include <hip/hip_runtime.h>
#include <hip/hip_bf16.h>

// MoE top-2-of-8 FFN + shared expert + router losses, MI355X gfx950.
// R5: router/scatter atomic de-serialization (274us -> noise).
// R8: m97-canonical 128^2 single-buffer GEMM at 4 blocks/CU (926us total).
// R9/R10 post-mortem: __launch_bounds__(256,5) forced VGPR to 48 < the 64
//     accumulator regs -> hipcc spilled acc to scratch -> 2.1 GB RMW traffic,
//     MfmaUtil 8%, ev 728us. (R9's atomic fusion compounded it: 1 GB RMW.)
//     RULE: this body needs ~128 unified regs; 5 waves/SIMD allows only 102.
// R11: ev reverted to (256,4); quantization fixed by ITEM SIZE not occupancy:
//     ev uses BN=64 tiles (128x64, acc[4][2]=32 regs, LDS 24KB). 2176 items
//     of T/2 -> ceil(2176/1024)=3 rounds of T/2 = 1.5T vs R8's 2T. Lower regs
//     (~100) + 24KB LDS may let HW fit 5-6 blocks/CU naturally (launch_bounds
//     is a floor). Everything else byte-identical to R10's non-ev parts.

#define N_TOK 8192
#define DM    1024
#define HD    4096
#define NE    8
#define NKTOT 16384            // N_TOK * 2
#define PERM_CAP 17408         // NKTOT + NE*128 (segment padding)
#define MAX_TILES 136          // sum ceil(T_e/128) <= NKTOT/128 + NE
#define BAND 17                // MAX_TILES / 8 xcds
#define RTOK_BLK 16            // router tokens per block

typedef __attribute__((ext_vector_type(8))) short bhalf8;
typedef __attribute__((ext_vector_type(8))) unsigned short ushort8v;
typedef __attribute__((ext_vector_type(4))) float floatx4;

__device__ __forceinline__ unsigned short f2bf(float f) {
  union { float f; unsigned int u; } v; v.f = f;
  unsigned int u = v.u;
  return (unsigned short)((u + 0x7fffu + ((u >> 16) & 1u)) >> 16);  // RNE
}

__device__ __forceinline__ float bf2f(unsigned short h) {
  union { unsigned int u; float f; } v; v.u = ((unsigned int)h) << 16;
  return v.f;
}

__device__ __forceinline__ float gelu_tanh(float h) {
  // jax.nn.gelu default (approximate=True)
  float u = 0.7978845608028654f * (h + 0.044715f * h * h * h);
  float t = 1.0f - 2.0f / (1.0f + __expf(2.0f * u));   // tanh(u)
  return 0.5f * h * (1.0f + t);
}

// global -> LDS direct DMA, 16B/lane. LDS dest is wave-uniform base + lane*16.
__device__ __forceinline__ void gload16(const unsigned short* g, void* l) {
  __builtin_amdgcn_global_load_lds(
      (const __attribute__((address_space(1))) void*)g,
      (__attribute__((address_space(3))) void*)l, 16, 0, 0);
}

// ---------------- init (ws is poisoned 0xAA each call) ----------------
__global__ void init_kernel(int* perm, float* permw, float* usage, float* zsum,
                            int* counts, int* fill) {
  int i = blockIdx.x * 256 + threadIdx.x;
  if (i < PERM_CAP) { perm[i] = 0; permw[i] = 0.0f; }
  if (i < NE) { usage[i] = 0.0f; counts[i] = 0; fill[i] = 0; }
  if (i == 0) zsum[0] = 0.0f;
}

// ---------------- x fp32 -> bf16 ----------------
__global__ void cvt_x_kernel(const float* __restrict__ x, unsigned short* __restrict__ xb) {
  size_t i = (size_t)(blockIdx.x * 256 + threadIdx.x) * 4;
  float4 v = *(const float4*)(x + i);
  ushort4 o;
  o.x = f2bf(v.x); o.y = f2bf(v.y); o.z = f2bf(v.z); o.w = f2bf(v.w);
  *(ushort4*)(xb + i) = o;
}

// ---------------- router: logits, top-2 softmax, aux-loss partials ----------------
__global__ void router_kernel(const float* __restrict__ x, const float* __restrict__ gw,
                              int* __restrict__ idxb, float* __restrict__ wbuf,
                              float* __restrict__ usage, float* __restrict__ zsum,
                              int* __restrict__ counts) {
  __shared__ float s_use[NE];
  __shared__ int   s_cnt[NE];
  __shared__ float s_z;
  int t = threadIdx.x;
  if (t < NE) { s_use[t] = 0.0f; s_cnt[t] = 0; }
  if (t == 0) s_z = 0.0f;
  __syncthreads();

  int wave = t >> 6;
  int lane = t & 63;

  float luse[NE]; int lcnt[NE];
#pragma unroll
  for (int e = 0; e < NE; e++) { luse[e] = 0.0f; lcnt[e] = 0; }
  float lz = 0.0f;

#pragma unroll
  for (int i = 0; i < 4; i++) {
    int n = blockIdx.x * RTOK_BLK + wave * 4 + i;
    const float* xr = x + (size_t)n * DM;
    float acc[NE];
#pragma unroll
    for (int e = 0; e < NE; e++) acc[e] = 0.0f;
    for (int d = lane; d < DM; d += 64) {
      float xv = xr[d];
      const float* g = gw + (size_t)d * NE;
#pragma unroll
      for (int e = 0; e < NE; e++) acc[e] += xv * g[e];
    }
#pragma unroll
    for (int e = 0; e < NE; e++) {
#pragma unroll
      for (int off = 32; off > 0; off >>= 1) acc[e] += __shfl_xor(acc[e], off);
    }
    if (lane == 0) {
      float m1 = acc[0]; int i1 = 0;
#pragma unroll
      for (int e = 1; e < NE; e++) if (acc[e] > m1) { m1 = acc[e]; i1 = e; }
      float m2 = -3.0e38f; int i2 = 0;
#pragma unroll
      for (int e = 0; e < NE; e++) if (e != i1 && acc[e] > m2) { m2 = acc[e]; i2 = e; }
      float e1 = __expf(m2 - m1);
      float w1 = 1.0f / (1.0f + e1);
      float w2 = e1 / (1.0f + e1);
      float s = 0.0f;
#pragma unroll
      for (int e = 0; e < NE; e++) s += __expf(acc[e] - m1);
      float lse = m1 + __logf(s);
      idxb[n * 2 + 0] = i1; idxb[n * 2 + 1] = i2;
      wbuf[n * 2 + 0] = w1; wbuf[n * 2 + 1] = w2;
      luse[i1] += w1; luse[i2] += w2;
      lcnt[i1]++;     lcnt[i2]++;
      lz += lse * lse;
    }
  }

  if (lane == 0) {
#pragma unroll
    for (int e = 0; e < NE; e++) {
      atomicAdd(&s_use[e], luse[e]);
      atomicAdd(&s_cnt[e], lcnt[e]);
    }
    atomicAdd(&s_z, lz);
  }
  __syncthreads();
  if (t < NE) {
    atomicAdd(&usage[t], s_use[t]);
    atomicAdd(&counts[t], s_cnt[t]);
  }
  if (t == 0) atomicAdd(zsum, s_z);
}

// ---------------- scan: padded segment offsets, tile table, router loss ----------------
__global__ void scan_kernel(const int* __restrict__ counts, int* __restrict__ poff,
                            int* __restrict__ tileE, int* __restrict__ tileR,
                            int* __restrict__ nTiles,
                            const float* __restrict__ usage, const float* __restrict__ zsum,
                            float* __restrict__ lossOut) {
  if (threadIdx.x == 0 && blockIdx.x == 0) {
    int run = 0, nt = 0;
    for (int e = 0; e < NE; e++) {
      poff[e] = run;
      int t = (counts[e] + 127) >> 7;
      for (int i = 0; i < t; i++) { tileE[nt] = e; tileR[nt] = run + i * 128; nt++; }
      run += t << 7;
    }
    *nTiles = nt;
    float mean = 0.0f;
    for (int e = 0; e < NE; e++) mean += usage[e];
    mean *= (1.0f / NE);
    float var = 0.0f;
    for (int e = 0; e < NE; e++) { float d = usage[e] - mean; var += d * d; }
    var *= (1.0f / NE);
    float bal = sqrtf(var) / mean * 0.01f;
    float z = (zsum[0] / (float)N_TOK) * 0.001f;
    lossOut[0] = bal + z;
  }
}

// ---------------- scatter tokens into per-expert segments ----------------
__global__ void scatter_kernel(const int* __restrict__ idxb, const float* __restrict__ wbuf,
                               const int* __restrict__ poff, int* __restrict__ fill,
                               int* __restrict__ perm, float* __restrict__ permw,
                               int* __restrict__ pos) {
  __shared__ int lcnt[NE];
  __shared__ int lbase[NE];
  int t = threadIdx.x;
  if (t < NE) lcnt[t] = 0;
  __syncthreads();
  int i = blockIdx.x * 256 + t;          // grid sized exactly: i < NKTOT
  int e = idxb[i];
  int r = atomicAdd(&lcnt[e], 1);        // LDS rank within block
  __syncthreads();
  if (t < NE) lbase[t] = atomicAdd(&fill[t], lcnt[t]);
  __syncthreads();
  int p = poff[e] + lbase[e] + r;
  perm[p] = i >> 1;
  permw[p] = wbuf[i];
  pos[i] = p;
}

// ---------------- transpose+convert: src fp32 [R][C] -> dst bf16 [C][R], batched ----------------
// dst writes vectorized: each lane stores ushort8 (16B). LDS read stride 65
// words -> 8 consecutive rows hit 8 distinct banks (conflict-free).
__global__ void transpose_cvt_kernel(const float* __restrict__ src,
                                     unsigned short* __restrict__ dst, int R, int C) {
  __shared__ float tile[64][65];
  size_t bo = (size_t)blockIdx.z * R * C;
  src += bo; dst += bo;
  int r0 = blockIdx.x * 64, c0 = blockIdx.y * 64;
  int c = threadIdx.x & 63, r = threadIdx.x >> 6;
#pragma unroll
  for (int i = 0; i < 16; i++)
    tile[r + i * 4][c] = src[(size_t)(r0 + r + i * 4) * C + c0 + c];
  __syncthreads();
  int u = threadIdx.x & 7;        // dst 8-col group (src row group)
  int ow = threadIdx.x >> 3;      // 0..31: dst row offset base
#pragma unroll
  for (int it = 0; it < 2; it++) {
    int oc = ow + it * 32;        // src col -> dst row offset
    ushort8v o;
#pragma unroll
    for (int j = 0; j < 8; j++) o[j] = f2bf(tile[u * 8 + j][oc]);
    *(ushort8v*)&dst[(size_t)(c0 + oc) * R + r0 + u * 8] = o;
  }
}

// ---------------- combine: out[t] += eout[pos0[t]] + eout[pos1[t]] ----------------
__global__ void combine_kernel(float* __restrict__ out,
                               const unsigned short* __restrict__ eout,
                               const int* __restrict__ pos) {
  int t = blockIdx.x;
  int d = threadIdx.x * 8;
  int p0 = pos[t * 2], p1 = pos[t * 2 + 1];
  float* o = out + (size_t)t * DM + d;
  const unsigned short* e0 = eout + (size_t)p0 * DM + d;
  const unsigned short* e1 = eout + (size_t)p1 * DM + d;
  float4 a = *(const float4*)(o);
  float4 b = *(const float4*)(o + 4);
  ushort4 u0a = *(const ushort4*)(e0), u0b = *(const ushort4*)(e0 + 4);
  ushort4 u1a = *(const ushort4*)(e1), u1b = *(const ushort4*)(e1 + 4);
  a.x += bf2f(u0a.x) + bf2f(u1a.x);
  a.y += bf2f(u0a.y) + bf2f(u1a.y);
  a.z += bf2f(u0a.z) + bf2f(u1a.z);
  a.w += bf2f(u0a.w) + bf2f(u1a.w);
  b.x += bf2f(u0b.x) + bf2f(u1b.x);
  b.y += bf2f(u0b.y) + bf2f(u1b.y);
  b.z += bf2f(u0b.z) + bf2f(u1b.z);
  b.w += bf2f(u0b.w) + bf2f(u1b.w);
  *(float4*)(o) = a;
  *(float4*)(o + 4) = b;
}

// ---------------- 128x128xBK64 bf16 MFMA GEMM, m97-canonical single buffer ----------------
// 256 threads = 4 waves (2x2 of 64x64 wave tiles). LDS: A[128][64]+B[128][64]
// bf16 = 32 KB. Per K-step: stage (8 x global_load_lds dwordx4) ->
// __syncthreads (drains vmcnt) -> 2x 16x16x32 k-steps of 4x4 MFMA ->
// __syncthreads. Stage drain hidden by co-resident sibling blocks (TLP).
template<int MODE>
__device__ __forceinline__ void gemm_body(
    const unsigned short* __restrict__ A,
    const unsigned short* __restrict__ BT,
    const float* __restrict__ bias,
    float* __restrict__ outF,
    unsigned short* __restrict__ outH,
    int Kd, int Nd,
    const int* __restrict__ perm,
    const float* __restrict__ permw,
    const int* __restrict__ tileE,
    const int* __restrict__ tileR,
    const int* __restrict__ nTiles) {
  __shared__ __align__(16) unsigned short As[128 * 64];
  __shared__ __align__(16) unsigned short Bs[128 * 64];

  int id = blockIdx.x;
  int xcd = id & 7, q = id >> 3;
  int mt, ntile;
  if (MODE == 0) {              // band 8m, m-fastest: pin A-band + B-slab in L2
    mt = xcd * 8 + (q & 7);
    ntile = q >> 3;
  } else if (MODE == 1) {       // band 8m, n-fastest
    ntile = q & 7;
    mt = xcd * 8 + (q >> 3);
  } else {                      // band 17m, supertile 4m x 8n
    int n_in = q & 7, m_in = (q >> 3) & 3, ng = (q >> 5) & 3, mg = q >> 7;
    int mband = mg * 4 + m_in;
    if (mband >= BAND) return;
    mt = xcd * BAND + mband;
    ntile = ng * 8 + n_in;
  }

  int n0 = ntile * 128;
  int prow0 = 0, m0 = 0;
  if (MODE >= 2) {
    if (mt >= *nTiles) return;
    int e = tileE[mt];
    prow0 = tileR[mt];
    BT += (size_t)e * Kd * Nd;
    bias += (size_t)e * Nd;
  } else {
    m0 = mt * 128;
  }

  int t = threadIdx.x;
  int rsub = t >> 3;               // 0..31: row within 32-row staging slab
  int gc = (t & 7) ^ (rsub & 7);   // swizzled global 16B-chunk index
  const unsigned short* aptr[4];
  const unsigned short* bptr[4];
#pragma unroll
  for (int p = 0; p < 4; p++) {
    int r = rsub + p * 32;
    size_t grow;
    if (MODE == 2)      grow = (size_t)perm[prow0 + r];
    else                grow = (size_t)(m0 + r);
    aptr[p] = A + grow * Kd + gc * 8;
    bptr[p] = BT + (size_t)(n0 + r) * Kd + gc * 8;
  }
  // wave-uniform LDS staging bases (lane*16 is added by HW)
  char* ldsA = (char*)As + (t & 192) * 16;
  char* ldsB = (char*)Bs + (t & 192) * 16;

  int lane = t & 63;
  int wv = t >> 6;
  int wm = (wv >> 1) * 64, wn = (wv & 1) * 64;
  int lr = lane & 15, lq = lane >> 4;
  int rx = lr & 7;                  // read-side row XOR key

  floatx4 acc[4][4];
#pragma unroll
  for (int i = 0; i < 4; i++)
#pragma unroll
    for (int j = 0; j < 4; j++) acc[i][j] = (floatx4){0.f, 0.f, 0.f, 0.f};

  for (int k0 = 0; k0 < Kd; k0 += 64) {
#pragma unroll
    for (int p = 0; p < 4; p++) {
      gload16(aptr[p] + k0, ldsA + p * 4096);
      gload16(bptr[p] + k0, ldsB + p * 4096);
    }
    __syncthreads();               // drains vmcnt(0): tile staged
#pragma unroll
    for (int kk = 0; kk < 2; kk++) {       // two 16x16x32 k-steps
      int ca = kk * 4 + lq;                // global chunk for this frag
      bhalf8 af[4], bf[4];
#pragma unroll
      for (int i = 0; i < 4; i++) {
        af[i] = *(const bhalf8*)&As[(wm + i * 16 + lr) * 64 + ((ca ^ rx) * 8)];
        bf[i] = *(const bhalf8*)&Bs[(wn + i * 16 + lr) * 64 + ((ca ^ rx) * 8)];
      }
#pragma unroll
      for (int mtile = 0; mtile < 4; mtile++)
#pragma unroll
        for (int ntl = 0; ntl < 4; ntl++)
          acc[mtile][ntl] = __builtin_amdgcn_mfma_f32_16x16x32_bf16(af[mtile], bf[ntl], acc[mtile][ntl], 0, 0, 0);
    }
    __syncthreads();               // protect buffer before next stage
  }

  // epilogue: D[row=(lane>>4)*4+reg][col=lane&15]
#pragma unroll
  for (int mtile = 0; mtile < 4; mtile++) {
#pragma unroll
    for (int ntl = 0; ntl < 4; ntl++) {
      int ncol = n0 + wn + ntl * 16 + lr;
      float bb = bias[ncol];
#pragma unroll
      for (int r = 0; r < 4; r++) {
        int mrow = wm + mtile * 16 + lq * 4 + r;    // local row 0..127
        float v = acc[mtile][ntl][r] + bb;
        if (MODE == 0) {
          outH[(size_t)(m0 + mrow) * Nd + ncol] = f2bf(gelu_tanh(v));
        } else if (MODE == 1) {
          outF[(size_t)(m0 + mrow) * Nd + ncol] = v;
        } else {
          outH[(size_t)(prow0 + mrow) * Nd + ncol] = f2bf(gelu_tanh(v));
        }
      }
    }
  }
}

// ---------------- expert_values: 128x64xBK64, acc[4][2]=32 regs, LDS 24KB ----------------
// Same staging/swizzle scheme; B uses 2 slabs (64 rows). Items are half-size
// so grid quantization costs 3 half-rounds (1.5T) instead of 2 full (2T).
// Low regs (~100 unified) + 24KB LDS may let HW fit >4 blocks/CU naturally.
__device__ __forceinline__ void gemm_body_ev(
    const unsigned short* __restrict__ A,
    const unsigned short* __restrict__ BT,
    const float* __restrict__ bias,
    unsigned short* __restrict__ outH,
    int Kd, int Nd,
    const float* __restrict__ permw,
    const int* __restrict__ tileE,
    const int* __restrict__ tileR,
    const int* __restrict__ nTiles) {
  __shared__ __align__(16) unsigned short As[128 * 64];   // 16 KB
  __shared__ __align__(16) unsigned short Bs[64 * 64];    // 8 KB

  int id = blockIdx.x;
  int xcd = id & 7, q = id >> 3;          // q 0..271
  int mt = xcd * BAND + (q >> 4);         // n-fastest per m: pin A panel in L2
  int ntile = q & 15;
  if (mt >= *nTiles) return;
  int prow0 = tileR[mt];
  int e = tileE[mt];
  BT += (size_t)e * Kd * Nd;
  bias += (size_t)e * Nd;
  int n0 = ntile * 64;

  int t = threadIdx.x;
  int rsub = t >> 3;               // 0..31: row within 32-row staging slab
  int gc = (t & 7) ^ (rsub & 7);   // swizzled global 16B-chunk index
  const unsigned short* aptr[4];
  const unsigned short* bptr[2];
#pragma unroll
  for (int p = 0; p < 4; p++)
    aptr[p] = A + (size_t)(prow0 + rsub + p * 32) * Kd + gc * 8;
#pragma unroll
  for (int p = 0; p < 2; p++)
    bptr[p] = BT + (size_t)(n0 + rsub + p * 32) * Kd + gc * 8;
  char* ldsA = (char*)As + (t & 192) * 16;
  char* ldsB = (char*)Bs + (t & 192) * 16;

  int lane = t & 63;
  int wv = t >> 6;
  int wm = (wv >> 1) * 64, wn = (wv & 1) * 32;    // wave tile 64m x 32n
  int lr = lane & 15, lq = lane >> 4;
  int rx = lr & 7;

  floatx4 acc[4][2];
#pragma unroll
  for (int i = 0; i < 4; i++)
#pragma unroll
    for (int j = 0; j < 2; j++) acc[i][j] = (floatx4){0.f, 0.f, 0.f, 0.f};

  for (int k0 = 0; k0 < Kd; k0 += 64) {
#pragma unroll
    for (int p = 0; p < 4; p++) gload16(aptr[p] + k0, ldsA + p * 4096);
#pragma unroll
    for (int p = 0; p < 2; p++) gload16(bptr[p] + k0, ldsB + p * 4096);
    __syncthreads();
#pragma unroll
    for (int kk = 0; kk < 2; kk++) {
      int ca = kk * 4 + lq;
      bhalf8 af[4], bf[2];
#pragma unroll
      for (int i = 0; i < 4; i++)
        af[i] = *(const bhalf8*)&As[(wm + i * 16 + lr) * 64 + ((ca ^ rx) * 8)];
#pragma unroll
      for (int j = 0; j < 2; j++)
        bf[j] = *(const bhalf8*)&Bs[(wn + j * 16 + lr) * 64 + ((ca ^ rx) * 8)];
#pragma unroll
      for (int i = 0; i < 4; i++)
#pragma unroll
        for (int j = 0; j < 2; j++)
          acc[i][j] = __builtin_amdgcn_mfma_f32_16x16x32_bf16(af[i], bf[j], acc[i][j], 0, 0, 0);
    }
    __syncthreads();
  }

  // epilogue: weighted expert out (bf16), D[row=lq*4+r][col=lr]
#pragma unroll
  for (int i = 0; i < 4; i++) {
#pragma unroll
    for (int j = 0; j < 2; j++) {
      int ncol = n0 + wn + j * 16 + lr;
      float bb = bias[ncol];
#pragma unroll
      for (int r = 0; r < 4; r++) {
        int prow = prow0 + wm + i * 16 + lq * 4 + r;
        float w = permw[prow];
        float v = acc[i][j][r] + bb;
        outH[(size_t)prow * Nd + ncol] = f2bf(w * v);
      }
    }
  }
}

// distinct names per mode so rocprof shows the per-GEMM breakdown
__global__ __launch_bounds__(256, 4) void gemm_shared_keys(
    const unsigned short* A, const unsigned short* BT, const float* bias,
    float* outF, unsigned short* outH, int Kd, int Nd,
    const int* perm, const float* permw, const int* tE, const int* tR, const int* nT) {
  gemm_body<0>(A, BT, bias, outF, outH, Kd, Nd, perm, permw, tE, tR, nT);
}
__global__ __launch_bounds__(256, 4) void gemm_shared_values(
    const unsigned short* A, const unsigned short* BT, const float* bias,
    float* outF, unsigned short* outH, int Kd, int Nd,
    const int* perm, const float* permw, const int* tE, const int* tR, const int* nT) {
  gemm_body<1>(A, BT, bias, outF, outH, Kd, Nd, perm, permw, tE, tR, nT);
}
__global__ __launch_bounds__(256, 4) void gemm_expert_keys(
    const unsigned short* A, const unsigned short* BT, const float* bias,
    float* outF, unsigned short* outH, int Kd, int Nd,
    const int* perm, const float* permw, const int* tE, const int* tR, const int* nT) {
  gemm_body<2>(A, BT, bias, outF, outH, Kd, Nd, perm, permw, tE, tR, nT);
}
__global__ __launch_bounds__(256, 4) void gemm_expert_values(
    const unsigned short* A, const unsigned short* BT, const float* bias,
    float* outF, unsigned short* outH, int Kd, int Nd,
    const int* perm, const float* permw, const int* tE, const int* tR, const int* nT) {
  gemm_body_ev(A, BT, bias, outH, Kd, Nd, permw, tE, tR, nT);
}

extern "C" void kernel_launch(void* const* d_in, const int* in_sizes, int n_in,
                              void* d_out, int out_size, void* d_ws, size_t ws_size,
                              hipStream_t stream) {
  const float* x        = (const float*)d_in[0];
  const float* gate_w   = (const float*)d_in[1];
  const float* keys_w   = (const float*)d_in[2];
  const float* keys_b   = (const float*)d_in[3];
  const float* values_w = (const float*)d_in[4];
  const float* values_b = (const float*)d_in[5];
  const float* sk_w     = (const float*)d_in[6];
  const float* sk_b     = (const float*)d_in[7];
  const float* sv_w     = (const float*)d_in[8];
  const float* sv_b     = (const float*)d_in[9];
  float* out = (float*)d_out;

  char* p = (char*)d_ws;
  unsigned short* xb   = (unsigned short*)p; p += (size_t)N_TOK * DM * 2;     // 16 MB
  unsigned short* wt   = (unsigned short*)p; p += (size_t)NE * DM * HD * 2;   // 64 MB (phased)
  unsigned short* hid  = (unsigned short*)p; p += (size_t)PERM_CAP * HD * 2;  // 142.6 MB
  unsigned short* eout = (unsigned short*)p; p += (size_t)PERM_CAP * DM * 2;  // 35.7 MB
  int*   idxb   = (int*)p;   p += NKTOT * 4;
  float* wbuf   = (float*)p; p += NKTOT * 4;
  int*   perm   = (int*)p;   p += PERM_CAP * 4;
  float* permw  = (float*)p; p += PERM_CAP * 4;
  int*   pos    = (int*)p;   p += NKTOT * 4;
  int*   counts = (int*)p;   p += NE * 4;
  int*   fill   = (int*)p;   p += NE * 4;
  int*   poff   = (int*)p;   p += NE * 4;
  float* usage  = (float*)p; p += NE * 4;
  float* zsum   = (float*)p; p += 16;
  int*   tileE  = (int*)p;   p += MAX_TILES * 4;
  int*   tileR  = (int*)p;   p += MAX_TILES * 4;
  int*   nTiles = (int*)p;   p += 16;

  float* lossOut = out + (size_t)N_TOK * DM;

  // 1) init + convert + router
  init_kernel<<<(PERM_CAP + 255) / 256, 256, 0, stream>>>(perm, permw, usage, zsum, counts, fill);
  cvt_x_kernel<<<(N_TOK * DM / 4 + 255) / 256, 256, 0, stream>>>(x, xb);
  router_kernel<<<N_TOK / RTOK_BLK, 256, 0, stream>>>(x, gate_w, idxb, wbuf, usage, zsum, counts);
  scan_kernel<<<1, 64, 0, stream>>>(counts, poff, tileE, tileR, nTiles, usage, zsum, lossOut);
  scatter_kernel<<<NKTOT / 256, 256, 0, stream>>>(idxb, wbuf, poff, fill, perm, permw, pos);

  // 2) shared expert: hid = gelu(x @ Wk + b); out = hid @ Wv + b
  transpose_cvt_kernel<<<dim3(DM / 64, HD / 64, 1), 256, 0, stream>>>(sk_w, wt, DM, HD);
  gemm_shared_keys<<<2048, 256, 0, stream>>>(             // 8 xcd * 8 m * 32 n (2 exact rounds)
      xb, wt, sk_b, nullptr, hid, DM, HD, perm, permw, tileE, tileR, nTiles);
  transpose_cvt_kernel<<<dim3(HD / 64, DM / 64, 1), 256, 0, stream>>>(sv_w, wt, HD, DM);
  gemm_shared_values<<<512, 256, 0, stream>>>(            // 8 xcd * 8 m * 8 n
      hid, wt, sv_b, out, nullptr, HD, DM, perm, permw, tileE, tileR, nTiles);

  // 3) routed experts (grouped, sparse top-2)
  transpose_cvt_kernel<<<dim3(DM / 64, HD / 64, NE), 256, 0, stream>>>(keys_w, wt, DM, HD);
  gemm_expert_keys<<<5120, 256, 0, stream>>>(             // 8 xcd * 20(m pad) * 32 n
      xb, wt, keys_b, nullptr, hid, DM, HD, perm, permw, tileE, tileR, nTiles);
  transpose_cvt_kernel<<<dim3(HD / 64, DM / 64, NE), 256, 0, stream>>>(values_w, wt, HD, DM);
  gemm_expert_values<<<2176, 256, 0, stream>>>(           // 8 xcd * 17 m * 16 n (BN=64)
      hid, wt, values_b, nullptr, eout, HD, DM, perm, permw, tileE, tileR, nTiles);

  // 4) out += top-2 expert contributions
  combine_kernel<<<N_TOK, 128, 0, stream>>>(out, eout, pos);
}